// Round 2
// baseline (6306.278 us; speedup 1.0000x reference)
//
#include <hip/hip_runtime.h>
#include <hip/hip_bf16.h>
#include <cstdint>

#define DD 20
#define HID 30

__device__ __forceinline__ void load20(const float* __restrict__ p, float* r){
  const float4* q = (const float4*)p;
#pragma unroll
  for (int i=0;i<5;i++){ float4 v=q[i]; r[4*i+0]=v.x; r[4*i+1]=v.y; r[4*i+2]=v.z; r[4*i+3]=v.w; }
}

// Precompute W3cat = [w_past, w_now, w_future], AR[r][j] = sum_k rela[r][k]*w1[j][20+k],
// AQ[r][j] = sum_k rela[r][k]*w1[j][40+k]   (AR/AQ rows padded to 32 floats)
__global__ void k_prep(const float* __restrict__ rela, const float* __restrict__ w1,
                       const float* __restrict__ wp, const float* __restrict__ wn,
                       const float* __restrict__ wf,
                       float* __restrict__ W3, float* __restrict__ AR, float* __restrict__ AQ,
                       int nrel){
  int t = blockIdx.x*blockDim.x + threadIdx.x;
  if (t < 3*DD*DD){
    int s = t/(DD*DD), idx = t%(DD*DD);
    W3[t] = (s==0)?wp[idx]:((s==1)?wn[idx]:wf[idx]);
  }
  if (t < nrel*HID){
    int r=t/HID, j=t-r*HID;
    float sr=0.f, sq=0.f;
#pragma unroll
    for (int k=0;k<DD;k++){
      float e = rela[r*DD+k];
      sr += e*w1[j*3*DD + DD + k];
      sq += e*w1[j*3*DD + 2*DD + k];
    }
    AR[r*32+j]=sr; AQ[r*32+j]=sq;
  }
}

// RT[sel][r][t][:] = (rela[r] + time[t]) @ Wsel^T
__global__ void k_rt(const float* __restrict__ rela, const float* __restrict__ timee,
                     const float* __restrict__ W3, float* __restrict__ RT,
                     int nrel, int ntime){
  int row = blockIdx.x*blockDim.x+threadIdx.x;
  int tot = 3*nrel*ntime;
  if (row>=tot) return;
  int per = nrel*ntime;
  int sel = row/per; int rem = row - sel*per; int r = rem/ntime; int t = rem - r*ntime;
  float e[DD], tv[DD];
  load20(rela + (size_t)r*DD, e);
  load20(timee + (size_t)t*DD, tv);
#pragma unroll
  for (int k=0;k<DD;k++) e[k]+=tv[k];
  const float* W = W3 + sel*DD*DD;
  float o[DD];
#pragma unroll
  for (int i=0;i<DD;i++){
    const float4* wr = (const float4*)(W + i*DD);
    float s=0.f;
#pragma unroll
    for (int c=0;c<5;c++){ float4 w=wr[c]; s += e[4*c]*w.x + e[4*c+1]*w.y + e[4*c+2]*w.z + e[4*c+3]*w.w; }
    o[i]=s;
  }
  float4* op=(float4*)(RT + (size_t)row*DD);
#pragma unroll
  for (int c=0;c<5;c++){ float4 v; v.x=o[4*c]; v.y=o[4*c+1]; v.z=o[4*c+2]; v.w=o[4*c+3]; op[c]=v; }
}

// One edge per thread. HASH=false for layer 0 (hidden==0 -> pure table lookups).
template<bool HASH>
__global__ void __launch_bounds__(256) k_edge(
    const int* __restrict__ src, const int* __restrict__ dst,
    const int* __restrict__ rel, const int* __restrict__ qrel,
    const int* __restrict__ rtm,
    const float* __restrict__ hin, float* __restrict__ hout,
    const float* __restrict__ RT, const float* __restrict__ AR, const float* __restrict__ AQ,
    const float* __restrict__ w1, const float* __restrict__ w2, const float* __restrict__ W3,
    int E, int nrel, int ntime)
{
  __shared__ float sW1h[HID*DD];
  __shared__ float sW2[32];
  __shared__ float sW3[3*DD*DD];
  for (int t=threadIdx.x; t<HID*DD; t+=blockDim.x){ int j=t/DD,k=t-j*DD; sW1h[t]=w1[j*3*DD+k]; }
  if (threadIdx.x<HID) sW2[threadIdx.x]=w2[threadIdx.x];
  for (int t=threadIdx.x; t<3*DD*DD; t+=blockDim.x) sW3[t]=W3[t];
  __syncthreads();
  int e = blockIdx.x*blockDim.x+threadIdx.x;
  if (e>=E) return;
  int s=src[e], d=dst[e], r=rel[e], q=qrel[e], t=rtm[e];
  int sel = (t>0)?2:((t==0)?1:0);
  int ta = (t<0)?-t:t;

  float h[DD];
  if (HASH){
    load20(hin+(size_t)s*DD, h);
#pragma unroll
    for (int i=0;i<DD;i++) h[i]=fmaxf(h[i],0.01f*h[i]);   // leaky_relu folded into gather
  }

  // attention pre-activations: AR[rel] + AQ[qrel] (+ h @ w1h^T)
  float a[HID];
  {
    const float4* ap=(const float4*)(AR+(size_t)r*32);
    const float4* qp=(const float4*)(AQ+(size_t)q*32);
#pragma unroll
    for (int c=0;c<7;c++){
      float4 x=ap[c], y=qp[c];
      a[4*c+0]=x.x+y.x; a[4*c+1]=x.y+y.y; a[4*c+2]=x.z+y.z; a[4*c+3]=x.w+y.w;
    }
    float2 x=*(const float2*)(AR+(size_t)r*32+28);
    float2 y=*(const float2*)(AQ+(size_t)q*32+28);
    a[28]=x.x+y.x; a[29]=x.y+y.y;
  }
  if (HASH){
#pragma unroll
    for (int j=0;j<HID;j++){
      const float4* wr=(const float4*)&sW1h[j*DD];
      float sum=a[j];
#pragma unroll
      for (int c=0;c<5;c++){ float4 w=wr[c]; sum += h[4*c]*w.x+h[4*c+1]*w.y+h[4*c+2]*w.z+h[4*c+3]*w.w; }
      a[j]=sum;
    }
  }
  float z=0.f;
#pragma unroll
  for (int j=0;j<HID;j++) z += fmaxf(a[j],0.f)*sW2[j];
  float score = 1.f/(1.f+__expf(-z));

  // transformed = RT[sel][r][ta] (+ h @ Wsel^T)
  float tr[DD];
  load20(RT + ((size_t)(sel*nrel+r)*ntime + ta)*DD, tr);
  if (HASH){
    const float* Ws = sW3 + sel*DD*DD;
#pragma unroll
    for (int i=0;i<DD;i++){
      const float4* wr=(const float4*)(Ws+i*DD);
      float sum=tr[i];
#pragma unroll
      for (int c=0;c<5;c++){ float4 w=wr[c]; sum += h[4*c]*w.x+h[4*c+1]*w.y+h[4*c+2]*w.z+h[4*c+3]*w.w; }
      tr[i]=sum;
    }
  }

  float* o = hout + (size_t)d*DD;
#pragma unroll
  for (int i=0;i<DD;i++) atomicAdd(o+i, score*tr[i]);
}

__global__ void k_result(const float* __restrict__ h, const float* __restrict__ wcls,
                         const float* __restrict__ bcls, float* __restrict__ res, int N){
  int i = blockIdx.x*blockDim.x+threadIdx.x;
  if (i>=N) return;
  float acc = bcls[0];
  const float4* q=(const float4*)(h+(size_t)i*DD);
#pragma unroll
  for (int c=0;c<5;c++){
    float4 v=q[c];
    float x0=fmaxf(v.x,0.01f*v.x), x1=fmaxf(v.y,0.01f*v.y);
    float x2=fmaxf(v.z,0.01f*v.z), x3=fmaxf(v.w,0.01f*v.w);
    acc += x0*wcls[4*c]+x1*wcls[4*c+1]+x2*wcls[4*c+2]+x3*wcls[4*c+3];
  }
  res[i]=acc;
}

__global__ void k_scatter(const float* __restrict__ res, const int* __restrict__ nb,
                          const int* __restrict__ ne, const int* __restrict__ nentp,
                          float* __restrict__ out, int N){
  int i=blockIdx.x*blockDim.x+threadIdx.x;
  if (i>=N) return;
  long long stride = nentp[0];
  out[(long long)nb[i]*stride + ne[i]] = res[i];
}

extern "C" void kernel_launch(void* const* d_in, const int* in_sizes, int n_in,
                              void* d_out, int out_size, void* d_ws, size_t ws_size,
                              hipStream_t stream){
  const int*   src =(const int*)d_in[0];
  const int*   dst =(const int*)d_in[1];
  const int*   rel =(const int*)d_in[2];
  const int*   qrel=(const int*)d_in[3];
  const int*   rtm =(const int*)d_in[4];
  const int*   nb  =(const int*)d_in[5];
  const int*   ne  =(const int*)d_in[6];
  const float* rela=(const float*)d_in[7];
  const float* timee=(const float*)d_in[8];
  const float* w1  =(const float*)d_in[9];
  const float* w2  =(const float*)d_in[10];
  const float* wp  =(const float*)d_in[11];
  const float* wn  =(const float*)d_in[12];
  const float* wf  =(const float*)d_in[13];
  const float* wcls=(const float*)d_in[14];
  const float* bcls=(const float*)d_in[15];
  const int*   nentp=(const int*)d_in[17];

  const int Lc=3;
  int LE=in_sizes[0]; int E=LE/Lc;
  int N=in_sizes[5];
  int nrel=in_sizes[7]/DD;
  int ntime=in_sizes[8]/DD;

  auto al=[](size_t x){ return (x+(size_t)255)&~(size_t)255; };
  size_t szBuf=al((size_t)N*DD*4);
  size_t szRT =al((size_t)3*nrel*ntime*DD*4);
  size_t szA  =al((size_t)nrel*32*4);
  size_t szW3 =al((size_t)3*DD*DD*4);
  size_t szRes=al((size_t)N*4);
  size_t need = 2*szBuf+szRT+2*szA+szW3+szRes;

  char* base; float* res;
  if (ws_size>=need){ base=(char*)d_ws; res=nullptr; }
  else { base=(char*)d_out; res=(float*)d_ws; }   // fallback: scratch inside d_out, result in ws
  size_t off=0;
  float* buf0=(float*)(base+off); off+=szBuf;
  float* buf1=(float*)(base+off); off+=szBuf;
  float* RT  =(float*)(base+off); off+=szRT;
  float* AR  =(float*)(base+off); off+=szA;
  float* AQ  =(float*)(base+off); off+=szA;
  float* W3  =(float*)(base+off); off+=szW3;
  if (!res){ res=(float*)(base+off); off+=szRes; }

  dim3 blk(256);
  int prepTot = (3*DD*DD > nrel*HID) ? 3*DD*DD : nrel*HID;
  k_prep<<<dim3((prepTot+255)/256),blk,0,stream>>>(rela,w1,wp,wn,wf,W3,AR,AQ,nrel);
  int rtTot=3*nrel*ntime;
  k_rt<<<dim3((rtTot+255)/256),blk,0,stream>>>(rela,timee,W3,RT,nrel,ntime);

  dim3 egrid((E+255)/256);
  // layer 0 (hidden = 0)
  (void)hipMemsetAsync(buf0,0,(size_t)N*DD*4,stream);
  k_edge<false><<<egrid,blk,0,stream>>>(src,dst,rel,qrel,rtm,nullptr,buf0,RT,AR,AQ,w1,w2,W3,E,nrel,ntime);
  // layer 1
  (void)hipMemsetAsync(buf1,0,(size_t)N*DD*4,stream);
  k_edge<true><<<egrid,blk,0,stream>>>(src+(size_t)E,dst+(size_t)E,rel+(size_t)E,qrel+(size_t)E,rtm+(size_t)E,
                                       buf0,buf1,RT,AR,AQ,w1,w2,W3,E,nrel,ntime);
  // layer 2
  (void)hipMemsetAsync(buf0,0,(size_t)N*DD*4,stream);
  k_edge<true><<<egrid,blk,0,stream>>>(src+(size_t)2*E,dst+(size_t)2*E,rel+(size_t)2*E,qrel+(size_t)2*E,rtm+(size_t)2*E,
                                       buf1,buf0,RT,AR,AQ,w1,w2,W3,E,nrel,ntime);

  dim3 ngrid((N+255)/256);
  k_result<<<ngrid,blk,0,stream>>>(buf0,wcls,bcls,res,N);
  (void)hipMemsetAsync(d_out,0,(size_t)out_size*sizeof(float),stream);
  k_scatter<<<ngrid,blk,0,stream>>>(res,nb,ne,nentp,(float*)d_out,N);
}